// Round 4
// baseline (353.007 us; speedup 1.0000x reference)
//
#include <hip/hip_runtime.h>
#include <stdint.h>

#define CH 64
#define NPTS 500000
#define NTILE (NPTS / 32)      // 15625 point-tiles of 32
#define NSTEP 12
#define BLK 256
#define WPB (BLK / 64)         // waves per block

typedef float floatx16 __attribute__((ext_vector_type(16)));
typedef float f32x8 __attribute__((ext_vector_type(8)));
typedef __bf16 bf16x8 __attribute__((ext_vector_type(8)));

// pack two fp32 into (bf16(even) | bf16(odd)<<16) by byte-perm truncation
__device__ __forceinline__ unsigned pk(float odd, float even) {
    return __builtin_amdgcn_perm(__float_as_uint(odd), __float_as_uint(even), 0x07060302u);
}
// top-16-bit truncation of x as a float (the "hi" bf16 part, exactly representable)
__device__ __forceinline__ float hif(float x) {
    return __uint_as_float(__float_as_uint(x) & 0xffff0000u);
}

struct U16 { unsigned a, b, c, d; };
__device__ __forceinline__ bf16x8 asb4(unsigned x0, unsigned x1, unsigned x2, unsigned x3) {
    U16 t{x0, x1, x2, x3};
    return __builtin_bit_cast(bf16x8, t);
}
__device__ __forceinline__ bf16x8 asbu4(uint4 v) {
    return __builtin_bit_cast(bf16x8, v);
}

// ---------------------------------------------------------------------------
// Prep kernel: W[step][k][c_out] -> bf16 hi/lo A-fragments with the bit2<->bit3
// column permutation, in lane-contiguous per-step 16 KB groups.
// flat uint4 idx = s*1024 + ((pl*2+mt)*4+q)*64 + lane
// ---------------------------------------------------------------------------
__global__ void prep_weights(const float* __restrict__ W0,
                             const float* __restrict__ W1,
                             const float* __restrict__ W2,
                             uint4* __restrict__ wsA) {
    const int g  = blockIdx.x * blockDim.x + threadIdx.x;   // 0..12287
    const int mp = g & 31;
    const int h  = (g >> 5) & 1;
    const int q  = (g >> 6) & 3;
    const int mt = (g >> 8) & 1;
    const int pl = (g >> 9) & 1;
    const int s  = g >> 10;
    const float* Wb = (s % 3 == 0) ? W0 : ((s % 3 == 1) ? W1 : W2);
    const float* Ws = Wb + (s / 3) * CH * CH;
    const int m   = mt * 32 + mp;
    const int col = (m & ~12) | ((m & 4) << 1) | ((m & 8) >> 1);  // swap bits 2,3
    unsigned o[4];
    #pragma unroll
    for (int d = 0; d < 4; ++d) {
        float e = Ws[(16 * q + 8 * h + 2 * d) * CH + col];
        float v = Ws[(16 * q + 8 * h + 2 * d + 1) * CH + col];
        if (pl) { e = e - hif(e); v = v - hif(v); }   // lo plane
        o[d] = pk(v, e);
    }
    wsA[g] = make_uint4(o[0], o[1], o[2], o[3]);
}

// ---------------------------------------------------------------------------
// Main kernel: one wave = 32 points. Barrier-free: weight fragments double-
// buffered in REGISTERS (prefetched one full step ahead, per-register vmcnt),
// biases in LDS (staged once), acc ping-pong so B-fragments are built lazily
// per-q from the previous step's accumulators, overlapping the MFMA pipe.
// ---------------------------------------------------------------------------
__global__ __launch_bounds__(BLK, 2) void mlp12_mfma(
    const float* __restrict__ feat,
    const uint4* __restrict__ wsA,
    const float* __restrict__ b0,
    const float* __restrict__ b1,
    const float* __restrict__ b2,
    float* __restrict__ out)
{
    __shared__ __align__(16) float sBias[NSTEP * CH];   // 3 KB, staged once

    const int tid  = threadIdx.x;
    const int lane = tid & 63;
    int wid = blockIdx.x * WPB + (tid >> 6);
    if (wid > NTILE - 1) wid = NTILE - 1;   // tail waves redo last tile (benign)
    const int n = lane & 31;       // point within tile (MFMA col)
    const int h = lane >> 5;       // half-wave = k/channel bit3
    const size_t row = (size_t)(wid * 32 + n) * CH;

    // feature loads first (HBM latency overlaps everything below)
    float4 fa[4], fb[4];
    {
        const float* frow = feat + row + 8 * h;
        #pragma unroll
        for (int q = 0; q < 4; ++q) {
            fa[q] = *(const float4*)(frow + 16 * q);
            fb[q] = *(const float4*)(frow + 16 * q + 4);
        }
    }

    // prologue: step-0 A fragments into registers
    uint4 Abuf[2][16];
    #pragma unroll
    for (int g = 0; g < 16; ++g) Abuf[0][g] = wsA[g * 64 + lane];

    // stage all biases into LDS (once per block)
    #pragma unroll
    for (int t = tid; t < NSTEP * CH; t += BLK) {
        const int s = t >> 6;
        const float* bs = ((s % 3 == 0) ? b0 : (s % 3 == 1) ? b1 : b2) + (s / 3) * CH;
        sBias[t] = bs[t & 63];
    }
    __syncthreads();   // the only barrier in the kernel

    floatx16 acc[2][2];   // [pingpong][mtile]

    #pragma unroll
    for (int s = 0; s < NSTEP; ++s) {
        const int p   = s & 1;     // A register buffer in use
        const int dst = s & 1;     // acc set written this step
        const int src = dst ^ 1;   // acc set holding previous step's result

        // prefetch next step's A fragments (consumed next iter -> full-step lead)
        if (s + 1 < NSTEP) {
            const uint4* wn = wsA + (size_t)(s + 1) * 1024;
            #pragma unroll
            for (int g = 0; g < 16; ++g) Abuf[p ^ 1][g] = wn[g * 64 + lane];
        }

        // init acc[dst] from bias (LDS, ~60 cyc, issued at step start)
        {
            const float* bb = &sBias[s * CH];
            f32x8 c0a = *(const f32x8*)(bb + 8 * h);
            f32x8 c0b = *(const f32x8*)(bb + 16 + 8 * h);
            f32x8 c1a = *(const f32x8*)(bb + 32 + 8 * h);
            f32x8 c1b = *(const f32x8*)(bb + 48 + 8 * h);
            #pragma unroll
            for (int j = 0; j < 8; ++j) {
                acc[dst][0][j]     = c0a[j];
                acc[dst][0][8 + j] = c0b[j];
                acc[dst][1][j]     = c1a[j];
                acc[dst][1][8 + j] = c1b[j];
            }
        }

        const bool relu = (s % 3 == 2);  // previous step had ReLU

        // 4 q-groups: lazy B-build (VALU overlaps MFMA pipe), then 6 MFMAs
        #pragma unroll
        for (int q = 0; q < 4; ++q) {
            unsigned bhq[4], blq[4];
            if (s == 0) {
                float e0 = fa[q].x, o0 = fa[q].y, e1 = fa[q].z, o1 = fa[q].w;
                float e2 = fb[q].x, o2 = fb[q].y, e3 = fb[q].z, o3 = fb[q].w;
                bhq[0] = pk(o0, e0); bhq[1] = pk(o1, e1);
                bhq[2] = pk(o2, e2); bhq[3] = pk(o3, e3);
                blq[0] = pk(o0 - hif(o0), e0 - hif(e0));
                blq[1] = pk(o1 - hif(o1), e1 - hif(e1));
                blq[2] = pk(o2 - hif(o2), e2 - hif(e2));
                blq[3] = pk(o3 - hif(o3), e3 - hif(e3));
            } else {
                const int rr = q & 1;
                #pragma unroll
                for (int d = 0; d < 4; ++d) {
                    float e = acc[src][q >> 1][8 * rr + 2 * d];
                    float o = acc[src][q >> 1][8 * rr + 2 * d + 1];
                    if (relu) { e = fmaxf(e, 0.f); o = fmaxf(o, 0.f); }
                    bhq[d] = pk(o, e);
                    blq[d] = pk(o - hif(o), e - hif(e));
                }
            }
            bf16x8 bh = asb4(bhq[0], bhq[1], bhq[2], bhq[3]);
            bf16x8 bl = asb4(blq[0], blq[1], blq[2], blq[3]);
            // idx(pl,mt,q) = (pl*2+mt)*4+q ; terms: hi_w*hi_x + lo_w*hi_x + hi_w*lo_x
            acc[dst][0] = __builtin_amdgcn_mfma_f32_32x32x16_bf16(asbu4(Abuf[p][q]),      bh, acc[dst][0], 0, 0, 0);
            acc[dst][1] = __builtin_amdgcn_mfma_f32_32x32x16_bf16(asbu4(Abuf[p][4 + q]),  bh, acc[dst][1], 0, 0, 0);
            acc[dst][0] = __builtin_amdgcn_mfma_f32_32x32x16_bf16(asbu4(Abuf[p][8 + q]),  bh, acc[dst][0], 0, 0, 0);
            acc[dst][1] = __builtin_amdgcn_mfma_f32_32x32x16_bf16(asbu4(Abuf[p][12 + q]), bh, acc[dst][1], 0, 0, 0);
            acc[dst][0] = __builtin_amdgcn_mfma_f32_32x32x16_bf16(asbu4(Abuf[p][q]),      bl, acc[dst][0], 0, 0, 0);
            acc[dst][1] = __builtin_amdgcn_mfma_f32_32x32x16_bf16(asbu4(Abuf[p][4 + q]),  bl, acc[dst][1], 0, 0, 0);
        }
    }

    // step 11 wrote acc[1]; store, un-permuting C row rho -> channel pi(rho)
    float* orow = out + row;
    #pragma unroll
    for (int rq = 0; rq < 4; ++rq) {
        float4 v0, v1;
        v0.x = acc[1][0][4 * rq + 0]; v0.y = acc[1][0][4 * rq + 1];
        v0.z = acc[1][0][4 * rq + 2]; v0.w = acc[1][0][4 * rq + 3];
        v1.x = acc[1][1][4 * rq + 0]; v1.y = acc[1][1][4 * rq + 1];
        v1.z = acc[1][1][4 * rq + 2]; v1.w = acc[1][1][4 * rq + 3];
        const int off = 16 * (rq >> 1) + 8 * h + 4 * (rq & 1);
        *(float4*)(orow + off)      = v0;
        *(float4*)(orow + 32 + off) = v1;
    }
}

extern "C" void kernel_launch(void* const* d_in, const int* in_sizes, int n_in,
                              void* d_out, int out_size, void* d_ws, size_t ws_size,
                              hipStream_t stream) {
    const float* feat = (const float*)d_in[0];
    // d_in[1] = points, d_in[2] = nuv — dead inputs
    const float* W0 = (const float*)d_in[3];
    const float* b0 = (const float*)d_in[4];
    const float* W1 = (const float*)d_in[5];
    const float* b1 = (const float*)d_in[6];
    const float* W2 = (const float*)d_in[7];
    const float* b2 = (const float*)d_in[8];
    float* out = (float*)d_out;
    uint4* wsA = (uint4*)d_ws;   // 12288 * 16B = 192 KiB of scratch

    prep_weights<<<48, 256, 0, stream>>>(W0, W1, W2, wsA);

    const int grid = (NTILE + WPB - 1) / WPB;
    mlp12_mfma<<<grid, BLK, 0, stream>>>(feat, wsA, b0, b1, b2, out);
}